// Round 13
// baseline (110.552 us; speedup 1.0000x reference)
//
#include <hip/hip_runtime.h>

// N=1536 T=20 H=64 E=16 M=128
// Qf[j,k] (32x32-MFMA-frag-tile layout), P[j,k]: fp16 in d_ws; W2f:
// pre-fragmented W2 (16KB fp16). out[i] = max_j relu( relu(Q[j]-P[i]) @ W2 + b2 )
//
// R15: 32x32x16 MFMA engine. R14 killed the latency theory (counted vmcnt
// = null). Surviving model: MFMA ISSUE occupancy -- each 16x16x32 MFMA
// holds the issue slot ~its full execution (VALUBusy 50% = 35% MFMA + 15%
// VALU), so the 48-MFMA/tile issue stream itself is the wall. 32x32x16:
// 2x FLOP per issue event (32768 vs 16384) + faster pipe (2495 vs 2075 TF
// ubench) => floor 18.6 -> 15.5us and issue events halve.
// Per wave: NI=1, 32-j tiles, 2 col-tiles x 8 k-steps = 16 MFMA/tile.
// Per-lane row-max only per tile (cross-lane shfl deferred to end).
// Scaffold = R13 (best): plain ping-pong loads, byte addr, parity stagger,
// setprio, deferred b2/relu. ~206 live regs -> honest 2 waves/SIMD.

#define NN 1536
#define HH 64
#define EE 16
#define MM 128
#define TT 20

#define JSPLIT 2
#define NT32 (NN / 32)        // 48 32-j tiles total
#define NTILE (NT32 / JSPLIT) // 24 tiles per wave
#define HTILE (NTILE / 2)     // 12 per half-run

typedef _Float16 half8 __attribute__((ext_vector_type(8)));
typedef float f32x16 __attribute__((ext_vector_type(16)));

// grid NN, block 128. Computes Qf (32x32 frag layout), P, W2f, zero-inits out.
// 32x32x16 A-frag: lane l holds row=l&31, k=(l>>5)*8+jj (K=16 per step).
// Element (j, m): ks=m>>4, hi=(m>>3)&1, jj=m&7, l=hi*32+(j&31);
//   Qf[(((j>>5)*8 + ks)*64 + l)*8 + jj]  (unit = 16B, tile = 8KB)
__global__ __launch_bounds__(128) void precompute_kernel(
    const float* __restrict__ hidden, const float* __restrict__ gt,
    const float* __restrict__ We, const float* __restrict__ be,
    const float* __restrict__ W1, const float* __restrict__ b1,
    const float* __restrict__ W2,
    _Float16* __restrict__ Qf, _Float16* __restrict__ P,
    _Float16* __restrict__ W2f, float* __restrict__ out)
{
  const int j = blockIdx.x;
  const int m = threadIdx.x;
  const float* hrow = hidden + j * HH;
  float a0 = 0.f, a1 = 0.f;
  #pragma unroll 8
  for (int h = 0; h < HH; h += 2) {
    a0 = fmaf(hrow[h],     W1[h * MM + m],       a0);
    a1 = fmaf(hrow[h + 1], W1[(h + 1) * MM + m], a1);
  }
  const float a = a0 + a1;
  float ve0 = 0.f, ve1 = 0.f, cm = b1[m];
  #pragma unroll
  for (int e = 0; e < EE; ++e) {
    float w1e = W1[(HH + e) * MM + m];
    ve0 = fmaf(We[e], w1e, ve0);       // We[0][e]
    ve1 = fmaf(We[EE + e], w1e, ve1);  // We[1][e]
    cm  = fmaf(be[e], w1e, cm);
  }
  const float e0 = gt[j * (2 * TT) + 2 * (TT - 1)];
  const float e1 = gt[j * (2 * TT) + 2 * (TT - 1) + 1];
  const float p = fmaf(e0, ve0, e1 * ve1);
  P[j * MM + m] = (_Float16)p;

  const int ks = m >> 4;
  const int hi = (m >> 3) & 1;
  const int jj = m & 7;
  const int l  = hi * 32 + (j & 31);
  Qf[((((j >> 5) * 8) + ks) * 64 + l) * 8 + jj] = (_Float16)(a + p + cm);

  if (m < HH) out[j * HH + m] = 0.f;

  // blocks 0..7: pre-fragment W2 for 32x32x16 B-frag:
  // col=l&31 (+ct*32), k=ks*16+(l>>5)*8+jj. unit u=(ct*8+ks)*64+l:
  // W2f[u*8+jj] = (fp16) W2[(ks*16 + (l>>5)*8 + jj)*HH + ct*32 + (l&31)]
  if (j < 8) {
    const int u = j * 128 + m;          // 0..1023
    const int ct = u >> 9;
    const int ksx = (u >> 6) & 7;
    const int lx = u & 63;
    half8 w;
    #pragma unroll
    for (int t = 0; t < 8; ++t)
      w[t] = (_Float16)W2[(ksx * 16 + (lx >> 5) * 8 + t) * HH + ct * 32 + (lx & 31)];
    *(half8*)(W2f + (size_t)u * 8) = w;
  }
}

// grid NN*JSPLIT = 3072, block 64 (1 wave). Wave: one i, 24 32-j tiles in
// two half-runs of 12 (parity stagger), plain ping-pong loads.
__global__ __launch_bounds__(64, 2) void pairmlp_max_kernel(
    const _Float16* __restrict__ Qf, const _Float16* __restrict__ P,
    const _Float16* __restrict__ W2f, const float* __restrict__ b2,
    float* __restrict__ out)
{
  const int lane = threadIdx.x;
  const int lc32 = lane & 31;
  const int hi   = lane >> 5;
  const int i  = blockIdx.x % NN;   // consecutive blocks: same js ->
  const int js = blockIdx.x / NN;   // same Q tile stream (L1/L2 reuse)
  const int par = blockIdx.x & 1;   // stagger parity

  // B fragments: 2 ct x 8 ks, coalesced 16B loads (64 VGPR)
  half8 bfrag[2][8];
  {
    const half8* wf = (const half8*)W2f + lane;
    #pragma unroll
    for (int ct = 0; ct < 2; ++ct)
      #pragma unroll
      for (int ks = 0; ks < 8; ++ks)
        bfrag[ct][ks] = wf[(ct * 8 + ks) * 64];
  }

  // P fragment: pv[ks] halfs jj -> P[i][ks*16 + hi*8 + jj]  (32 VGPR)
  half8 pv[8];
  {
    const _Float16* prow = P + i * MM + hi * 8;
    #pragma unroll
    for (int ks = 0; ks < 8; ++ks)
      pv[ks] = *(const half8*)(prow + ks * 16);
  }

  float b2v[2];
  #pragma unroll
  for (int ct = 0; ct < 2; ++ct) b2v[ct] = b2[ct * 32 + lc32];

  // per-lane running max over this lane's 16 C-rows (cross-lane merge at end)
  float rmax[2] = {-3.0e38f, -3.0e38f};

  // byte base: tile jt at jt*8192, ks at +1024*ks, lane at +16*lane
  const char* qbytes = (const char*)Qf + (size_t)(js * NTILE) * 8192 + lane * 16;

  const half8 hz = 0;
  const f32x16 fz = {0.f,0.f,0.f,0.f,0.f,0.f,0.f,0.f,0.f,0.f,0.f,0.f,0.f,0.f,0.f,0.f};

  // compute one 32-j tile held in qt[8] against this wave's i
  auto compute_tile = [&](const half8* qt) {
    f32x16 acc0, acc1;
    __builtin_amdgcn_s_setprio(1);
    {
      half8 s = qt[0] - pv[0];
      s = __builtin_elementwise_max(s, hz);
      acc0 = __builtin_amdgcn_mfma_f32_32x32x16_f16(s, bfrag[0][0], fz, 0, 0, 0);
      acc1 = __builtin_amdgcn_mfma_f32_32x32x16_f16(s, bfrag[1][0], fz, 0, 0, 0);
    }
    #pragma unroll
    for (int ks = 1; ks < 8; ++ks) {
      half8 s = qt[ks] - pv[ks];
      s = __builtin_elementwise_max(s, hz);
      acc0 = __builtin_amdgcn_mfma_f32_32x32x16_f16(s, bfrag[0][ks], acc0, 0, 0, 0);
      acc1 = __builtin_amdgcn_mfma_f32_32x32x16_f16(s, bfrag[1][ks], acc1, 0, 0, 0);
    }
    __builtin_amdgcn_s_setprio(0);
    // C/D: col=lc32(+ct*32), row=(reg&3)+8*(reg>>2)+4*hi -- 16 distinct rows
    // per lane; lane-local max only (rows l vs l^32 merged once at the end).
    float m0a = fmaxf(fmaxf(acc0[0], acc0[1]), fmaxf(acc0[2], acc0[3]));
    float m0b = fmaxf(fmaxf(acc0[4], acc0[5]), fmaxf(acc0[6], acc0[7]));
    float m0c = fmaxf(fmaxf(acc0[8], acc0[9]), fmaxf(acc0[10], acc0[11]));
    float m0d = fmaxf(fmaxf(acc0[12], acc0[13]), fmaxf(acc0[14], acc0[15]));
    rmax[0] = fmaxf(rmax[0], fmaxf(fmaxf(m0a, m0b), fmaxf(m0c, m0d)));
    float m1a = fmaxf(fmaxf(acc1[0], acc1[1]), fmaxf(acc1[2], acc1[3]));
    float m1b = fmaxf(fmaxf(acc1[4], acc1[5]), fmaxf(acc1[6], acc1[7]));
    float m1c = fmaxf(fmaxf(acc1[8], acc1[9]), fmaxf(acc1[10], acc1[11]));
    float m1d = fmaxf(fmaxf(acc1[12], acc1[13]), fmaxf(acc1[14], acc1[15]));
    rmax[1] = fmaxf(rmax[1], fmaxf(fmaxf(m1a, m1b), fmaxf(m1c, m1d)));
  };

  half8 qc[8], qn[8];

  // two half-runs of HTILE tiles; order swapped by parity (anti-phase stagger)
  for (int h = 0; h < 2; ++h) {
    const char* runb = qbytes + (((h ^ par) != 0) ? HTILE * 8192 : 0);
    const char* qp = runb;

    // prime qc from first tile of this run
    #pragma unroll
    for (int ks = 0; ks < 8; ++ks)
      qc[ks] = *(const half8*)(qp + ks * 1024);

    for (int t = 0; t < HTILE; t += 2) {
      // prefetch tile t+1 (imm offsets off qp+8192)
      #pragma unroll
      for (int ks = 0; ks < 8; ++ks)
        qn[ks] = *(const half8*)(qp + 8192 + ks * 1024);
      compute_tile(qc);  // tile t

      // prefetch tile t+2 (dummy run-start on last pair; unused)
      const char* q2 = (t + 2 < HTILE) ? (qp + 16384) : runb;
      #pragma unroll
      for (int ks = 0; ks < 8; ++ks)
        qc[ks] = *(const half8*)(q2 + ks * 1024);
      compute_tile(qn);  // tile t+1

      qp += 16384;
    }
  }

  // merge the two half-lane row-sets (rows +4: lane l vs l^32), b2, relu,
  // then atomic max (v >= 0 so uint-compare atomicMax is monotone-safe).
  #pragma unroll
  for (int ct = 0; ct < 2; ++ct) {
    float v = rmax[ct];
    v = fmaxf(v, __shfl_xor(v, 32, 64));
    v = fmaxf(v + b2v[ct], 0.f);
    if (hi == 0)
      atomicMax((unsigned*)(out + i * HH + ct * 32 + lc32), __float_as_uint(v));
  }
}

extern "C" void kernel_launch(void* const* d_in, const int* in_sizes, int n_in,
                              void* d_out, int out_size, void* d_ws, size_t ws_size,
                              hipStream_t stream) {
  const float* hidden = (const float*)d_in[0];
  const float* gt     = (const float*)d_in[1];
  const float* We     = (const float*)d_in[2];
  const float* be     = (const float*)d_in[3];
  const float* W1     = (const float*)d_in[4];
  const float* b1     = (const float*)d_in[5];
  const float* W2     = (const float*)d_in[6];
  const float* b2     = (const float*)d_in[7];
  float* out = (float*)d_out;

  _Float16* Qf  = (_Float16*)d_ws;     // NN*MM fp16 (384KB), 32x32 frag layout
  _Float16* Ph  = Qf + NN * MM;        // NN*MM fp16 (384KB)
  _Float16* W2f = Ph + NN * MM;        // 2*8*64*8 fp16 (16KB), 32x32 frag layout

  precompute_kernel<<<NN, 128, 0, stream>>>(hidden, gt, We, be, W1, b1, W2, Qf, Ph, W2f, out);
  pairmlp_max_kernel<<<NN * JSPLIT, 64, 0, stream>>>(Qf, Ph, W2f, b2, out);
}